// Round 1
// baseline (2009.988 us; speedup 1.0000x reference)
//
#include <hip/hip_runtime.h>

#define USER_NUM   100000
#define ITEM_NUM   50000
#define N_NODES    (USER_NUM + ITEM_NUM)
#define NNZ        4800000
#define EMB        64
#define N_LAYERS   3
#define EPS_F      0.2f
#define NORM_EPS_F 1e-12f

#define SCAN_TPB    1024
#define SCAN_BLOCKS ((N_NODES + SCAN_TPB - 1) / SCAN_TPB)   // 147
static_assert(SCAN_BLOCKS <= 256, "scan2 single block assumption");

// ---------------- helpers ----------------

__global__ void zero_ints(int* __restrict__ p, int n) {
    int i = blockIdx.x * blockDim.x + threadIdx.x;
    int stride = gridDim.x * blockDim.x;
    for (; i < n; i += stride) p[i] = 0;
}

// histogram of row indices
__global__ void hist_kernel(const int* __restrict__ rows, int* __restrict__ counts) {
    int i = blockIdx.x * blockDim.x + threadIdx.x;
    int stride = gridDim.x * blockDim.x;
    for (; i < NNZ; i += stride) atomicAdd(&counts[rows[i]], 1);
}

// block-local exclusive scan; block totals to bsums
__global__ __launch_bounds__(SCAN_TPB) void scan1_kernel(const int* __restrict__ counts,
                                                         int* __restrict__ row_ptr,
                                                         int* __restrict__ bsums) {
    __shared__ int s[SCAN_TPB];
    int tid = threadIdx.x;
    int i = blockIdx.x * SCAN_TPB + tid;
    int c = (i < N_NODES) ? counts[i] : 0;
    s[tid] = c;
    __syncthreads();
    for (int off = 1; off < SCAN_TPB; off <<= 1) {
        int t = (tid >= off) ? s[tid - off] : 0;
        __syncthreads();
        s[tid] += t;
        __syncthreads();
    }
    if (i < N_NODES) row_ptr[i] = s[tid] - c;   // exclusive
    if (tid == SCAN_TPB - 1) bsums[blockIdx.x] = s[tid];
}

// single-block exclusive scan of block sums
__global__ __launch_bounds__(256) void scan2_kernel(int* __restrict__ bsums, int n) {
    __shared__ int s[256];
    int tid = threadIdx.x;
    int c = (tid < n) ? bsums[tid] : 0;
    s[tid] = c;
    __syncthreads();
    for (int off = 1; off < 256; off <<= 1) {
        int t = (tid >= off) ? s[tid - off] : 0;
        __syncthreads();
        s[tid] += t;
        __syncthreads();
    }
    if (tid < n) bsums[tid] = s[tid] - c;       // exclusive
}

// add block offsets, set sentinel
__global__ __launch_bounds__(SCAN_TPB) void scan3_kernel(int* __restrict__ row_ptr,
                                                         const int* __restrict__ bsums) {
    int i = blockIdx.x * SCAN_TPB + threadIdx.x;
    if (i < N_NODES) row_ptr[i] += bsums[blockIdx.x];
    else if (i == N_NODES) row_ptr[i] = NNZ;
}

// scatter edges into CSR order, packing (col, val) into int2
__global__ void scatter_kernel(const int* __restrict__ rows, const int* __restrict__ cols,
                               const float* __restrict__ vals,
                               const int* __restrict__ row_ptr, int* __restrict__ fill,
                               int2* __restrict__ edges) {
    int i = blockIdx.x * blockDim.x + threadIdx.x;
    int stride = gridDim.x * blockDim.x;
    for (; i < NNZ; i += stride) {
        int r = rows[i];
        int pos = row_ptr[r] + atomicAdd(&fill[r], 1);
        edges[pos] = make_int2(cols[i], __float_as_int(vals[i]));
    }
}

// ego0 = concat(user_emb, item_emb), float4-vectorized
__global__ void concat_kernel(const float4* __restrict__ u, const float4* __restrict__ it,
                              float4* __restrict__ ego) {
    const int n_u = USER_NUM * EMB / 4;
    const int n_t = N_NODES * EMB / 4;
    int i = blockIdx.x * blockDim.x + threadIdx.x;
    int stride = gridDim.x * blockDim.x;
    for (; i < n_t; i += stride) ego[i] = (i < n_u) ? u[i] : it[i - n_u];
}

// one wave (64 lanes) per row: CSR SpMM + fused sign-perturbation + mean accumulation
// mode 0: out = v, x_out = v
// mode 1: out += v, x_out = v
// mode 2: out = (out + v) / 3   (x_out unused)
__global__ __launch_bounds__(256) void spmm_layer_kernel(const float* __restrict__ x,
                                                         float* __restrict__ x_out,
                                                         const int* __restrict__ row_ptr,
                                                         const int2* __restrict__ edges,
                                                         const float* __restrict__ noise_k,
                                                         float* __restrict__ out, int mode) {
    int wave_in_blk = threadIdx.x >> 6;
    int lane = threadIdx.x & 63;
    int row = blockIdx.x * (blockDim.x >> 6) + wave_in_blk;
    if (row >= N_NODES) return;

    int beg = row_ptr[row];
    int end = row_ptr[row + 1];

    float acc = 0.f;
    for (int e = beg; e < end; ++e) {
        int2 ed = edges[e];                          // wave-uniform broadcast load
        float v = __int_as_float(ed.y);
        acc += v * x[(long)ed.x * EMB + lane];       // coalesced 256B gather
    }

    // perturbation: acc + sign(acc) * (r / max(||r||, eps)) * EPS
    float r = noise_k[(long)row * EMB + lane];
    float ss = r * r;
#pragma unroll
    for (int off = 32; off >= 1; off >>= 1) ss += __shfl_xor(ss, off, 64);
    float denom = fmaxf(sqrtf(ss), NORM_EPS_F);
    float runit = r / denom;
    float sgn = (acc > 0.f) ? 1.f : ((acc < 0.f) ? -1.f : 0.f);
    float v = acc + sgn * runit * EPS_F;

    long idx = (long)row * EMB + lane;
    if (mode == 0) {
        out[idx] = v;
        x_out[idx] = v;
    } else if (mode == 1) {
        out[idx] += v;
        x_out[idx] = v;
    } else {
        out[idx] = (out[idx] + v) * (1.f / 3.f);
    }
}

// ---------------- launch ----------------

extern "C" void kernel_launch(void* const* d_in, const int* in_sizes, int n_in,
                              void* d_out, int out_size, void* d_ws, size_t ws_size,
                              hipStream_t stream) {
    const float* user_emb = (const float*)d_in[0];
    const float* item_emb = (const float*)d_in[1];
    const int*   adj_rows = (const int*)d_in[2];
    const int*   adj_cols = (const int*)d_in[3];
    const float* adj_vals = (const float*)d_in[4];
    const float* noise    = (const float*)d_in[5];
    float* out = (float*)d_out;

    // workspace layout (16B-aligned chunks)
    char* ws = (char*)d_ws;
    size_t off = 0;
    auto alloc = [&](size_t bytes) {
        char* p = ws + off;
        off += (bytes + 15) & ~size_t(15);
        return p;
    };
    int*   row_ptr = (int*)alloc((N_NODES + 1) * sizeof(int));
    int*   fill    = (int*)alloc(N_NODES * sizeof(int));
    int*   bsums   = (int*)alloc(256 * sizeof(int));
    int2*  edges   = (int2*)alloc((size_t)NNZ * sizeof(int2));
    float* ego_a   = (float*)alloc((size_t)N_NODES * EMB * sizeof(float));
    float* ego_b   = (float*)alloc((size_t)N_NODES * EMB * sizeof(float));

    // ---- CSR build ----
    zero_ints<<<587, 256, 0, stream>>>(fill, N_NODES);
    hist_kernel<<<4096, 256, 0, stream>>>(adj_rows, fill);
    scan1_kernel<<<SCAN_BLOCKS, SCAN_TPB, 0, stream>>>(fill, row_ptr, bsums);
    scan2_kernel<<<1, 256, 0, stream>>>(bsums, SCAN_BLOCKS);
    scan3_kernel<<<SCAN_BLOCKS, SCAN_TPB, 0, stream>>>(row_ptr, bsums);
    zero_ints<<<587, 256, 0, stream>>>(fill, N_NODES);
    scatter_kernel<<<4096, 256, 0, stream>>>(adj_rows, adj_cols, adj_vals,
                                             row_ptr, fill, edges);

    // ---- ego0 = concat ----
    concat_kernel<<<4096, 256, 0, stream>>>((const float4*)user_emb,
                                            (const float4*)item_emb, (float4*)ego_a);

    // ---- 3 layers, 4 waves (rows) per 256-thread block ----
    const int LGRID = (N_NODES + 3) / 4;   // 37500
    const size_t NE = (size_t)N_NODES * EMB;
    spmm_layer_kernel<<<LGRID, 256, 0, stream>>>(ego_a, ego_b, row_ptr, edges,
                                                 noise + 0 * NE, out, 0);
    spmm_layer_kernel<<<LGRID, 256, 0, stream>>>(ego_b, ego_a, row_ptr, edges,
                                                 noise + 1 * NE, out, 1);
    spmm_layer_kernel<<<LGRID, 256, 0, stream>>>(ego_a, nullptr, row_ptr, edges,
                                                 noise + 2 * NE, out, 2);
}

// Round 2
// 1455.734 us; speedup vs baseline: 1.3807x; 1.3807x over previous
//
#include <hip/hip_runtime.h>

#define USER_NUM   100000
#define ITEM_NUM   50000
#define N_NODES    (USER_NUM + ITEM_NUM)
#define NNZ        4800000
#define EMB        64
#define N_LAYERS   3
#define EPS_F      0.2f
#define NORM_EPS_F 1e-12f

#define SCAN_TPB    1024
#define SCAN_BLOCKS ((N_NODES + SCAN_TPB - 1) / SCAN_TPB)   // 147
static_assert(SCAN_BLOCKS <= 256, "scan2 single block assumption");

// ---------------- CSR build ----------------

__global__ void zero_ints(int* __restrict__ p, int n) {
    int i = blockIdx.x * blockDim.x + threadIdx.x;
    int stride = gridDim.x * blockDim.x;
    for (; i < n; i += stride) p[i] = 0;
}

__global__ void hist_kernel(const int* __restrict__ rows, int* __restrict__ counts) {
    int i = blockIdx.x * blockDim.x + threadIdx.x;
    int stride = gridDim.x * blockDim.x;
    for (; i < NNZ; i += stride) atomicAdd(&counts[rows[i]], 1);
}

__global__ __launch_bounds__(SCAN_TPB) void scan1_kernel(const int* __restrict__ counts,
                                                         int* __restrict__ row_ptr,
                                                         int* __restrict__ bsums) {
    __shared__ int s[SCAN_TPB];
    int tid = threadIdx.x;
    int i = blockIdx.x * SCAN_TPB + tid;
    int c = (i < N_NODES) ? counts[i] : 0;
    s[tid] = c;
    __syncthreads();
    for (int off = 1; off < SCAN_TPB; off <<= 1) {
        int t = (tid >= off) ? s[tid - off] : 0;
        __syncthreads();
        s[tid] += t;
        __syncthreads();
    }
    if (i < N_NODES) row_ptr[i] = s[tid] - c;   // exclusive
    if (tid == SCAN_TPB - 1) bsums[blockIdx.x] = s[tid];
}

__global__ __launch_bounds__(256) void scan2_kernel(int* __restrict__ bsums, int n) {
    __shared__ int s[256];
    int tid = threadIdx.x;
    int c = (tid < n) ? bsums[tid] : 0;
    s[tid] = c;
    __syncthreads();
    for (int off = 1; off < 256; off <<= 1) {
        int t = (tid >= off) ? s[tid - off] : 0;
        __syncthreads();
        s[tid] += t;
        __syncthreads();
    }
    if (tid < n) bsums[tid] = s[tid] - c;       // exclusive
}

// add block offsets; ALSO copy result into fill[] (scatter cursor) and set sentinel
__global__ __launch_bounds__(SCAN_TPB) void scan3_kernel(int* __restrict__ row_ptr,
                                                         const int* __restrict__ bsums,
                                                         int* __restrict__ fill) {
    int i = blockIdx.x * SCAN_TPB + threadIdx.x;
    if (i < N_NODES) {
        int v = row_ptr[i] + bsums[blockIdx.x];
        row_ptr[i] = v;
        fill[i] = v;
    } else if (i == N_NODES) {
        row_ptr[i] = NNZ;
    }
}

// scatter edges into CSR order; fill[] starts at row_ptr[], used as cursor
__global__ void scatter_kernel(const int* __restrict__ rows, const int* __restrict__ cols,
                               const float* __restrict__ vals,
                               int* __restrict__ fill, int2* __restrict__ edges) {
    int i = blockIdx.x * blockDim.x + threadIdx.x;
    int stride = gridDim.x * blockDim.x;
    for (; i < NNZ; i += stride) {
        int pos = atomicAdd(&fill[rows[i]], 1);
        edges[pos] = make_int2(cols[i], __float_as_int(vals[i]));
    }
}

// ---------------- SpMM + perturbation + mean ----------------
// One wave (64 lanes = 64 dims) per row. x is given as (xu, xi) pair so layer 0
// can read user_emb/item_emb directly without materializing the concat.
// mode 0: out = v, x_out = v
// mode 1: out += v, x_out = v
// mode 2: out = (out + v) / 3
__global__ __launch_bounds__(256) void spmm_layer_kernel(const float* __restrict__ xu,
                                                         const float* __restrict__ xi,
                                                         float* __restrict__ x_out,
                                                         const int* __restrict__ row_ptr,
                                                         const int2* __restrict__ edges,
                                                         const float* __restrict__ noise_k,
                                                         float* __restrict__ out, int mode) {
    int lane = threadIdx.x & 63;
    int row = blockIdx.x * (blockDim.x >> 6) + (threadIdx.x >> 6);
    if (row >= N_NODES) return;

    int beg = row_ptr[row];
    int end = row_ptr[row + 1];

    float a0 = 0.f, a1 = 0.f, a2 = 0.f, a3 = 0.f;
    float a4 = 0.f, a5 = 0.f, a6 = 0.f, a7 = 0.f;

    for (int base = beg; base < end; base += 8) {
        int lim = end - 1;
        // 8 clamped, unconditional edge loads (wave-uniform addresses)
        int2 e0 = edges[min(base + 0, lim)];
        int2 e1 = edges[min(base + 1, lim)];
        int2 e2 = edges[min(base + 2, lim)];
        int2 e3 = edges[min(base + 3, lim)];
        int2 e4 = edges[min(base + 4, lim)];
        int2 e5 = edges[min(base + 5, lim)];
        int2 e6 = edges[min(base + 6, lim)];
        int2 e7 = edges[min(base + 7, lim)];
        // 8 independent coalesced gathers in flight
        const float* p0 = (e0.x < USER_NUM) ? (xu + (long)e0.x * EMB) : (xi + (long)(e0.x - USER_NUM) * EMB);
        const float* p1 = (e1.x < USER_NUM) ? (xu + (long)e1.x * EMB) : (xi + (long)(e1.x - USER_NUM) * EMB);
        const float* p2 = (e2.x < USER_NUM) ? (xu + (long)e2.x * EMB) : (xi + (long)(e2.x - USER_NUM) * EMB);
        const float* p3 = (e3.x < USER_NUM) ? (xu + (long)e3.x * EMB) : (xi + (long)(e3.x - USER_NUM) * EMB);
        const float* p4 = (e4.x < USER_NUM) ? (xu + (long)e4.x * EMB) : (xi + (long)(e4.x - USER_NUM) * EMB);
        const float* p5 = (e5.x < USER_NUM) ? (xu + (long)e5.x * EMB) : (xi + (long)(e5.x - USER_NUM) * EMB);
        const float* p6 = (e6.x < USER_NUM) ? (xu + (long)e6.x * EMB) : (xi + (long)(e6.x - USER_NUM) * EMB);
        const float* p7 = (e7.x < USER_NUM) ? (xu + (long)e7.x * EMB) : (xi + (long)(e7.x - USER_NUM) * EMB);
        float x0 = p0[lane], x1 = p1[lane], x2 = p2[lane], x3 = p3[lane];
        float x4 = p4[lane], x5 = p5[lane], x6 = p6[lane], x7 = p7[lane];
        // zero the weights of the clamped (out-of-range) tail edges
        float w0 = __int_as_float(e0.y);
        float w1 = (base + 1 < end) ? __int_as_float(e1.y) : 0.f;
        float w2 = (base + 2 < end) ? __int_as_float(e2.y) : 0.f;
        float w3 = (base + 3 < end) ? __int_as_float(e3.y) : 0.f;
        float w4 = (base + 4 < end) ? __int_as_float(e4.y) : 0.f;
        float w5 = (base + 5 < end) ? __int_as_float(e5.y) : 0.f;
        float w6 = (base + 6 < end) ? __int_as_float(e6.y) : 0.f;
        float w7 = (base + 7 < end) ? __int_as_float(e7.y) : 0.f;
        a0 += w0 * x0; a1 += w1 * x1; a2 += w2 * x2; a3 += w3 * x3;
        a4 += w4 * x4; a5 += w5 * x5; a6 += w6 * x6; a7 += w7 * x7;
    }
    float acc = ((a0 + a1) + (a2 + a3)) + ((a4 + a5) + (a6 + a7));

    // perturbation: acc + sign(acc) * (r / max(||r||, eps)) * EPS
    float r = noise_k[(long)row * EMB + lane];
    float ss = r * r;
#pragma unroll
    for (int off = 32; off >= 1; off >>= 1) ss += __shfl_xor(ss, off, 64);
    float denom = fmaxf(sqrtf(ss), NORM_EPS_F);
    float sgn = (acc > 0.f) ? 1.f : ((acc < 0.f) ? -1.f : 0.f);
    float v = acc + sgn * (r / denom) * EPS_F;

    long idx = (long)row * EMB + lane;
    if (mode == 0) {
        out[idx] = v;
        x_out[idx] = v;
    } else if (mode == 1) {
        out[idx] += v;
        x_out[idx] = v;
    } else {
        out[idx] = (out[idx] + v) * (1.f / 3.f);
    }
}

// ---------------- launch ----------------

extern "C" void kernel_launch(void* const* d_in, const int* in_sizes, int n_in,
                              void* d_out, int out_size, void* d_ws, size_t ws_size,
                              hipStream_t stream) {
    const float* user_emb = (const float*)d_in[0];
    const float* item_emb = (const float*)d_in[1];
    const int*   adj_rows = (const int*)d_in[2];
    const int*   adj_cols = (const int*)d_in[3];
    const float* adj_vals = (const float*)d_in[4];
    const float* noise    = (const float*)d_in[5];
    float* out = (float*)d_out;

    char* ws = (char*)d_ws;
    size_t off = 0;
    auto alloc = [&](size_t bytes) {
        char* p = ws + off;
        off += (bytes + 15) & ~size_t(15);
        return p;
    };
    int*   row_ptr = (int*)alloc((N_NODES + 1) * sizeof(int));
    int*   fill    = (int*)alloc(N_NODES * sizeof(int));
    int*   bsums   = (int*)alloc(256 * sizeof(int));
    int2*  edges   = (int2*)alloc((size_t)NNZ * sizeof(int2));
    float* ego_a   = (float*)alloc((size_t)N_NODES * EMB * sizeof(float));
    float* ego_b   = (float*)alloc((size_t)N_NODES * EMB * sizeof(float));

    // ---- CSR build (5 kernels) ----
    zero_ints<<<587, 256, 0, stream>>>(fill, N_NODES);
    hist_kernel<<<4096, 256, 0, stream>>>(adj_rows, fill);
    scan1_kernel<<<SCAN_BLOCKS, SCAN_TPB, 0, stream>>>(fill, row_ptr, bsums);
    scan2_kernel<<<1, 256, 0, stream>>>(bsums, SCAN_BLOCKS);
    scan3_kernel<<<SCAN_BLOCKS, SCAN_TPB, 0, stream>>>(row_ptr, bsums, fill);
    scatter_kernel<<<4096, 256, 0, stream>>>(adj_rows, adj_cols, adj_vals, fill, edges);

    // ---- 3 layers; layer 0 reads user_emb/item_emb directly (no concat) ----
    const int LGRID = (N_NODES + 3) / 4;   // 4 waves (rows) per 256-thread block
    const size_t NE = (size_t)N_NODES * EMB;
    spmm_layer_kernel<<<LGRID, 256, 0, stream>>>(user_emb, item_emb, ego_a,
                                                 row_ptr, edges, noise + 0 * NE, out, 0);
    spmm_layer_kernel<<<LGRID, 256, 0, stream>>>(ego_a, ego_a + (size_t)USER_NUM * EMB, ego_b,
                                                 row_ptr, edges, noise + 1 * NE, out, 1);
    spmm_layer_kernel<<<LGRID, 256, 0, stream>>>(ego_b, ego_b + (size_t)USER_NUM * EMB, nullptr,
                                                 row_ptr, edges, noise + 2 * NE, out, 2);
}